// Round 4
// baseline (119138.025 us; speedup 1.0000x reference)
//
#include <hip/hip_runtime.h>
#include <stdint.h>

#define NW    284   // per-thread weight dwords (f16 pairs): 204 VGPR + 80 AGPR
#define NV    204   // layer-2 row dwords, arch-VGPR resident
#define NA    80    // tail dwords, AGPR resident
#define TMAIN 4096
#define TTOT  5120

typedef _Float16 f16;
typedef _Float16 f16x2 __attribute__((ext_vector_type(2)));

__device__ __forceinline__ float fdot2(uint32_t a, uint32_t b, float c) {
  return __builtin_amdgcn_fdot2(__builtin_bit_cast(f16x2, a),
                                __builtin_bit_cast(f16x2, b), c, false);
}
__device__ __forceinline__ uint32_t packf16(float a, float b) {
  f16x2 p = { (_Float16)a, (_Float16)b };
  return __builtin_bit_cast(uint32_t, p);
}
// AGPR accessors: force storage into the (otherwise idle) accumulator file.
__device__ __forceinline__ uint32_t aget(uint32_t a) {
  uint32_t v;
  asm("v_accvgpr_read_b32 %0, %1" : "=v"(v) : "a"(a));
  return v;
}
__device__ __forceinline__ uint32_t aput(uint32_t v) {
  uint32_t a;
  asm("v_accvgpr_write_b32 %0, %1" : "=a"(a) : "v"(v));
  return a;
}
__device__ __forceinline__ float sigm(float x) { return 1.f / (1.f + __expf(-x)); }
__device__ __forceinline__ float tanhfast(float x) { return 2.f / (1.f + __expf(-2.f * x)) - 1.f; }

// H slot map (f16 indices): h1 [0:152) (151+1 pad), h2 [152:408) (251+5 pad), h3 [408:464) (51+5 pad).
// Per-thread weight slots s in [0,568): s<408 = layer-2 row (aligned to H slots);
// tail k=s-408 in [0,160): role depends on thread id (see wslot).
__device__ float wslot(int t, int s,
                       const float* Wih1, const float* Whh1,
                       const float* Wih2, const float* Whh2,
                       const float* Wih3, const float* Whh3,
                       const float* Wl) {
  if (s < 408) {                       // layer-2 gate row t (t<1004)
    if (t >= 1004) return 0.f;
    if (s < 151) return Wih2[t * 151 + s];          // vs h1
    if (s < 152) return 0.f;                        // h1 pad
    int c = s - 152;
    return (c < 251) ? Whh2[t * 251 + c] : 0.f;     // vs h2 (+pad)
  }
  int k = s - 408;
  if (t < 604) {                       // layer-1 gate row t: [x0,x1, h1...]
    if (k < 2) return Wih1[t * 2 + k];
    int c = k - 2;
    return (c < 151) ? Whh1[t * 151 + c] : 0.f;
  }
  if (t < 1012) {                      // layer-3 half-rows: idx pairs split K
    int idx = t - 604, r = idx >> 1, hf = idx & 1;
    if (!hf) return Wih3[r * 251 + k];              // H slots [152:312): h2[0:160)
    if (k >= 152) return 0.f;
    int c = k + 160;                                // H slots [312:464)
    if (c < 251) return Wih3[r * 251 + c];
    if (c < 256) return 0.f;                        // h2 pad
    int c3 = c - 256;
    return (c3 < 51) ? Whh3[r * 51 + c3] : 0.f;     // vs h3 (+pad)
  }
  if (t < 1014) {                      // final linear rows over h3
    int r = t - 1012;
    return (k < 51) ? Wl[r * 51 + k] : 0.f;
  }
  return 0.f;
}

__global__ void prep(const float* __restrict__ x,
                     const float* __restrict__ Wih1, const float* __restrict__ Whh1,
                     const float* __restrict__ Wih2, const float* __restrict__ Whh2,
                     const float* __restrict__ Wih3, const float* __restrict__ Whh3,
                     const float* __restrict__ Wl,
                     uint32_t* __restrict__ ws_w, uint32_t* __restrict__ ws_x) {
  int b = blockIdx.x;
  if (b < 1024) {
    for (int i = threadIdx.x; i < NW; i += blockDim.x) {
      float v0 = wslot(b, 2 * i,     Wih1, Whh1, Wih2, Whh2, Wih3, Whh3, Wl);
      float v1 = wslot(b, 2 * i + 1, Wih1, Whh1, Wih2, Whh2, Wih3, Whh3, Wl);
      ws_w[(size_t)b * NW + i] = packf16(v0, v1);
    }
  } else {
    int i = (b - 1024) * 256 + threadIdx.x;
    if (i < TMAIN) ws_x[i] = packf16(x[2 * i], x[2 * i + 1]);
  }
}

__global__ __launch_bounds__(1024, 1) void lstm_seq(
    const uint32_t* __restrict__ ws_w, const uint32_t* __restrict__ ws_x,
    const float* __restrict__ bih1, const float* __restrict__ bhh1,
    const float* __restrict__ bih2, const float* __restrict__ bhh2,
    const float* __restrict__ bih3, const float* __restrict__ bhh3,
    const float* __restrict__ bl, float* __restrict__ out) {
  __shared__ __align__(16) f16 Hs[464];     // h1|h2|h3, padded, f16
  __shared__ uint32_t XL[TMAIN];            // x as f16 pairs
  __shared__ float G[1024];                 // gate staging
  __shared__ float bs1[604];
  __shared__ float bs2[1004];
  __shared__ float bs3[204];
  __shared__ float bsl[2];
  __shared__ float c1s[151], c2s[251], c3s[51];
  __shared__ uint32_t yfb;                  // feedback y as f16 pair

  const int tid = threadIdx.x;

  uint32_t W[NV];                           // layer-2 row: arch-VGPR resident
  uint32_t A[NA];                           // tail: AGPR resident
  {
    const uint4* src = (const uint4*)(ws_w + (size_t)tid * NW);
#pragma unroll
    for (int i = 0; i < NV / 4; ++i) {
      uint4 v = src[i];
      W[4*i+0] = v.x; W[4*i+1] = v.y; W[4*i+2] = v.z; W[4*i+3] = v.w;
    }
#pragma unroll
    for (int i = 0; i < NA / 4; ++i) {
      uint4 v = src[NV / 4 + i];
      A[4*i+0] = aput(v.x); A[4*i+1] = aput(v.y);
      A[4*i+2] = aput(v.z); A[4*i+3] = aput(v.w);
    }
  }
#pragma unroll
  for (int i = 0; i < 4; ++i) XL[tid + 1024 * i] = ws_x[tid + 1024 * i];
  if (tid < 604)  bs1[tid] = bih1[tid] + bhh1[tid];
  if (tid < 1004) bs2[tid] = bih2[tid] + bhh2[tid];
  if (tid < 204)  bs3[tid] = bih3[tid] + bhh3[tid];
  if (tid < 2)    bsl[tid] = bl[tid];
  if (tid < 232)  ((uint32_t*)Hs)[tid] = 0u;   // zero all 464 f16 (incl. pads)
  if (tid < 151)  c1s[tid] = 0.f;
  if (tid < 251)  c2s[tid] = 0.f;
  if (tid < 51)   c3s[tid] = 0.f;
  if (tid == 0)   yfb = 0u;
  __syncthreads();

  const uint4* Hp = (const uint4*)Hs;       // broadcast b128 view of activations

#pragma unroll 1
  for (int t = 0; t < TTOT; ++t) {
    // ---- phase 1: layer-1 gates (threads 0..603, one gate row each; reads h1(t-1))
    if (tid < 604) {
      uint32_t xin = (t < TMAIN) ? XL[t] : yfb;
      float g0 = fdot2(aget(A[0]), xin, bs1[tid]);
      float g1 = 0.f, g2 = 0.f, g3 = 0.f;
#pragma unroll
      for (int j = 0; j < 19; ++j) {
        uint4 hv = Hp[j];
        g0 = fdot2(aget(A[1+4*j+0]), hv.x, g0);
        g1 = fdot2(aget(A[1+4*j+1]), hv.y, g1);
        g2 = fdot2(aget(A[1+4*j+2]), hv.z, g2);
        g3 = fdot2(aget(A[1+4*j+3]), hv.w, g3);
      }
      G[tid] = (g0 + g1) + (g2 + g3);
    }
    __syncthreads();
    // ---- phase 2: layer-1 cell update
    if (tid < 151) {
      float gi = sigm(G[tid]);
      float gf = sigm(G[151 + tid]);
      float gg = tanhfast(G[302 + tid]);
      float go = sigm(G[453 + tid]);
      float c = gf * c1s[tid] + gi * gg;
      c1s[tid] = c;
      Hs[tid] = (f16)(go * tanhfast(c));
    }
    __syncthreads();
    // ---- phase 3: layer-2 gates (threads 0..1003; reads h1(t), h2(t-1))
    if (tid < 1004) {
      float g0 = bs2[tid], g1 = 0.f, g2 = 0.f, g3 = 0.f;
#pragma unroll
      for (int j = 0; j < 51; ++j) {
        uint4 hv = Hp[j];
        g0 = fdot2(W[4*j+0], hv.x, g0);
        g1 = fdot2(W[4*j+1], hv.y, g1);
        g2 = fdot2(W[4*j+2], hv.z, g2);
        g3 = fdot2(W[4*j+3], hv.w, g3);
      }
      G[tid] = (g0 + g1) + (g2 + g3);
    }
    __syncthreads();
    // ---- phase 4: layer-2 cell update
    if (tid < 251) {
      float gi = sigm(G[tid]);
      float gf = sigm(G[251 + tid]);
      float gg = tanhfast(G[502 + tid]);
      float go = sigm(G[753 + tid]);
      float c = gf * c2s[tid] + gi * gg;
      c2s[tid] = c;
      Hs[152 + tid] = (f16)(go * tanhfast(c));
    }
    __syncthreads();
    // ---- phase 5: layer-3 gates, K split over lane pairs (threads 604..1011)
    if (tid >= 604 && tid < 1012) {
      int idx = tid - 604, r = idx >> 1, hf = idx & 1;
      const uint4* hp = Hp + (hf ? 39 : 19);
      float g0 = hf ? 0.f : bs3[r];
      float g1 = 0.f, g2 = 0.f, g3 = 0.f;
#pragma unroll
      for (int j = 0; j < 19; ++j) {
        uint4 hv = hp[j];
        g0 = fdot2(aget(A[4*j+0]), hv.x, g0);
        g1 = fdot2(aget(A[4*j+1]), hv.y, g1);
        g2 = fdot2(aget(A[4*j+2]), hv.z, g2);
        g3 = fdot2(aget(A[4*j+3]), hv.w, g3);
      }
      if (!hf) {                       // half A has one extra b128 (20 vs 19)
        uint4 hv = Hp[38];
        g0 = fdot2(aget(A[76]), hv.x, g0);
        g1 = fdot2(aget(A[77]), hv.y, g1);
        g2 = fdot2(aget(A[78]), hv.z, g2);
        g3 = fdot2(aget(A[79]), hv.w, g3);
      }
      float s = (g0 + g1) + (g2 + g3);
      s += __shfl_xor(s, 1);           // combine K-halves (adjacent lanes)
      if (!hf) G[r] = s;
    }
    __syncthreads();
    // ---- phase 6: layer-3 cell update
    if (tid < 51) {
      float gi = sigm(G[tid]);
      float gf = sigm(G[51 + tid]);
      float gg = tanhfast(G[102 + tid]);
      float go = sigm(G[153 + tid]);
      float c = gf * c3s[tid] + gi * gg;
      c3s[tid] = c;
      Hs[408 + tid] = (f16)(go * tanhfast(c));
    }
    __syncthreads();
    // ---- phase 7: output linear (threads 1012,1013) + feedback
    if (tid >= 1012 && tid < 1014) {
      int r = tid - 1012;
      float g0 = bsl[r], g1 = 0.f, g2 = 0.f, g3 = 0.f;
#pragma unroll
      for (int j = 0; j < 7; ++j) {
        uint4 hv = Hp[51 + j];
        g0 = fdot2(aget(A[4*j+0]), hv.x, g0);
        g1 = fdot2(aget(A[4*j+1]), hv.y, g1);
        g2 = fdot2(aget(A[4*j+2]), hv.z, g2);
        g3 = fdot2(aget(A[4*j+3]), hv.w, g3);
      }
      float y = (g0 + g1) + (g2 + g3);
      out[2 * t + r] = y;
      float yo = __shfl_down(y, 1);
      if (r == 0) yfb = packf16(y, yo);
    }
    __syncthreads();
  }
}

extern "C" void kernel_launch(void* const* d_in, const int* in_sizes, int n_in,
                              void* d_out, int out_size, void* d_ws, size_t ws_size,
                              hipStream_t stream) {
  (void)in_sizes; (void)n_in; (void)out_size; (void)ws_size;
  const float* x    = (const float*)d_in[0];
  const float* Wih1 = (const float*)d_in[1];
  const float* Whh1 = (const float*)d_in[2];
  const float* bih1 = (const float*)d_in[3];
  const float* bhh1 = (const float*)d_in[4];
  const float* Wih2 = (const float*)d_in[5];
  const float* Whh2 = (const float*)d_in[6];
  const float* bih2 = (const float*)d_in[7];
  const float* bhh2 = (const float*)d_in[8];
  const float* Wih3 = (const float*)d_in[9];
  const float* Whh3 = (const float*)d_in[10];
  const float* bih3 = (const float*)d_in[11];
  const float* bhh3 = (const float*)d_in[12];
  const float* Wl   = (const float*)d_in[13];
  const float* bl   = (const float*)d_in[14];

  uint32_t* ws_w = (uint32_t*)d_ws;           // 1024 * 284 dwords
  uint32_t* ws_x = ws_w + 1024 * NW;          // 4096 dwords

  prep<<<1040, 256, 0, stream>>>(x, Wih1, Whh1, Wih2, Whh2, Wih3, Whh3, Wl, ws_w, ws_x);
  lstm_seq<<<1, 1024, 0, stream>>>(ws_w, ws_x, bih1, bhh1, bih2, bhh2, bih3, bhh3,
                                   bl, (float*)d_out);
}

// Round 5
// 49919.785 us; speedup vs baseline: 2.3866x; 2.3866x over previous
//
#include <hip/hip_runtime.h>
#include <stdint.h>

// ---------------- problem constants ----------------
#define T_MAIN 4096
#define T_TOT  5120
#define NTHR   512
#define STRD   184              // packed weight dwords per lstm thread (16B aligned)

// ws layout (dword offsets)
#define WS_W    0               // 5*512*184 = 471040
#define WS_X    471040          // 4096
#define WS_H1   475136          // 5121*76
#define WS_H2   864332          // 5121*126
#define WS_H3   1509578         // 5121*26
#define WS_Y    1642724         // 5120
#define WS_PROG 1647872         // 13*32 (128B-strided counters)
// prog slots: h1[w]=w*32, h2[w]=(4+w)*32, h3[w]=(8+w)*32, y=12*32

typedef _Float16 f16;
typedef _Float16 f16x2 __attribute__((ext_vector_type(2)));

__device__ __forceinline__ float fdot2(uint32_t a, uint32_t b, float c) {
  return __builtin_amdgcn_fdot2(__builtin_bit_cast(f16x2, a),
                                __builtin_bit_cast(f16x2, b), c, false);
}
__device__ __forceinline__ uint32_t packf16(float a, float b) {
  f16x2 p = { (_Float16)a, (_Float16)b };
  return __builtin_bit_cast(uint32_t, p);
}
__device__ __forceinline__ uint16_t f16b(float v) {
  return __builtin_bit_cast(uint16_t, (_Float16)v);
}
__device__ __forceinline__ float sigm(float x) { return 1.f / (1.f + __expf(-x)); }
__device__ __forceinline__ float tanhfast(float x) { return 2.f / (1.f + __expf(-2.f * x)) - 1.f; }

// ---------------- weight packing map ----------------
// Per lstm thread (wg<4):
//   dwords [0,104):   L2 half-row (if lt < 8*u2): half-local f16 slots s=2d,2d+1 in [0,208);
//                     valid s<202 -> K-slot k = half*202+s of K=404 layout
//                     (k<151: Wih2[R][k]; k==151: pad; 152<=k<403: Whh2[R][k-152]; 403: pad)
//   dwords [104,181): L1 row (lt < 4*u1): s2 in [0,154): k=s2
//                     (k<151: Whh1[R][k]; 151: pad; 152,153: Wih1[R][k-152])
//                  OR L3 half-row (152<=lt<152+8*u3): s2 in [0,152): k = half*152+s2 of K=304
//                     (k<251: Wih3[R][k]; 251: pad; 252<=k<303: Whh3[R][k-252]; 303: pad)
// wg==4: dwords [0,16): Wl half-row (lt<4): k = half*26+s, s<26, k<51 -> Wl[r][k]
__device__ float slotv(int wg, int lt, int s,
                       const float* Wih1, const float* Whh1,
                       const float* Wih2, const float* Whh2,
                       const float* Wih3, const float* Whh3,
                       const float* Wl) {
  if (wg == 4) {
    if (lt < 4 && s < 26) {
      int r = lt >> 1, half = lt & 1;
      int k = half * 26 + s;
      if (k < 51) return Wl[r * 51 + k];
    }
    return 0.f;
  }
  const int u1 = (wg < 3) ? 38 : 37, b1u = 38 * wg;
  const int u2 = (wg < 3) ? 63 : 62, b2u = 63 * wg;
  const int u3 = (wg < 3) ? 13 : 12, b3u = 13 * wg;
  if (s < 208) {                      // L2 region
    if (lt < 8 * u2 && s < 202) {
      int r2 = lt >> 1, half = lt & 1;
      int g = (r2 >= u2) + (r2 >= 2 * u2) + (r2 >= 3 * u2);
      int un = r2 - g * u2;
      int R = g * 251 + b2u + un;
      int k = half * 202 + s;
      if (k < 151) return Wih2[R * 151 + k];
      if (k == 151) return 0.f;
      if (k < 403) return Whh2[R * 251 + (k - 152)];
    }
    return 0.f;
  }
  int s2 = s - 208;                   // [0,154)
  if (lt < 4 * u1) {                  // L1 row
    int g = (lt >= u1) + (lt >= 2 * u1) + (lt >= 3 * u1);
    int un = lt - g * u1;
    int R = g * 151 + b1u + un;
    if (s2 < 151) return Whh1[R * 151 + s2];
    if (s2 == 151) return 0.f;
    if (s2 < 154) return Wih1[R * 2 + (s2 - 152)];
    return 0.f;
  }
  if (lt >= 152 && lt < 152 + 8 * u3 && s2 < 152) {   // L3 half-row
    int tt = lt - 152, r3 = tt >> 1, half = tt & 1;
    int g = (r3 >= u3) + (r3 >= 2 * u3) + (r3 >= 3 * u3);
    int un = r3 - g * u3;
    int R = g * 51 + b3u + un;
    int k = half * 152 + s2;
    if (k < 251) return Wih3[R * 251 + k];
    if (k == 251) return 0.f;
    if (k < 303) return Whh3[R * 51 + (k - 252)];
    return 0.f;
  }
  return 0.f;
}

__global__ void prep(const float* __restrict__ x,
                     const float* __restrict__ Wih1, const float* __restrict__ Whh1,
                     const float* __restrict__ Wih2, const float* __restrict__ Whh2,
                     const float* __restrict__ Wih3, const float* __restrict__ Whh3,
                     const float* __restrict__ Wl,
                     uint32_t* __restrict__ ws) {
  int b = blockIdx.x, lt = threadIdx.x;   // blockDim = 64
  if (b < 2560) {                          // pack weights: b = wg*512 + lstm_tid
    int wg = b >> 9, lth = b & 511;
    uint32_t* dst = ws + WS_W + (size_t)b * STRD;
    for (int d = lt; d < STRD; d += 64) {
      float v0 = slotv(wg, lth, 2 * d,     Wih1, Whh1, Wih2, Whh2, Wih3, Whh3, Wl);
      float v1 = slotv(wg, lth, 2 * d + 1, Wih1, Whh1, Wih2, Whh2, Wih3, Whh3, Wl);
      dst[d] = packf16(v0, v1);
    }
  } else if (b < 2624) {                   // x -> f16 pairs
    int i = (b - 2560) * 64 + lt;
    if (i < T_MAIN) ws[WS_X + i] = packf16(x[2 * i], x[2 * i + 1]);
  } else {                                 // init state & counters
    for (int i = lt; i < 76;  i += 64) ws[WS_H1 + i] = 0u;
    for (int i = lt; i < 126; i += 64) ws[WS_H2 + i] = 0u;
    for (int i = lt; i < 26;  i += 64) ws[WS_H3 + i] = 0u;
    for (int i = lt; i < 416; i += 64) ws[WS_PROG + i] = 0u;
  }
}

// lane-0-only spin with monotone-counter cache; sets *ab instead of hanging
__device__ __forceinline__ void waitge(uint32_t* p, unsigned* cache, unsigned tgt, int* ab) {
  if (*cache >= tgt || *ab) return;
  int polls = 0;
  for (;;) {
    unsigned v = __hip_atomic_load(p, __ATOMIC_ACQUIRE, __HIP_MEMORY_SCOPE_AGENT);
    if (v >= tgt) { *cache = v; return; }
    if (++polls > 3000000) { *ab = 1; return; }
  }
}

__global__ __launch_bounds__(NTHR, 2) void lstm5(
    uint32_t* __restrict__ ws,
    const float* __restrict__ bih1, const float* __restrict__ bhh1,
    const float* __restrict__ bih2, const float* __restrict__ bhh2,
    const float* __restrict__ bih3, const float* __restrict__ bhh3,
    const float* __restrict__ bl, float* __restrict__ out) {
  const int wg = blockIdx.x;
  const int lt = threadIdx.x;
  uint32_t* const h1g = ws + WS_H1;
  uint32_t* const h2g = ws + WS_H2;
  uint32_t* const h3g = ws + WS_H3;
  uint32_t* const yg  = ws + WS_Y;
  uint32_t* const pg  = ws + WS_PROG;
  const uint32_t* const xg = ws + WS_X;

  __shared__ __align__(16) uint32_t Vec1[80];
  __shared__ __align__(16) uint32_t Vec2[208];
  __shared__ __align__(16) uint32_t Vec3[152];
  __shared__ __align__(16) uint32_t Vecy[32];
  __shared__ float G[256];
  __shared__ float bs1f[152], bs2f[252], bs3f[52], bsly[2];
  __shared__ int aborted;

  // ---- load packed weights into registers (static-indexed only) ----
  uint32_t W2[104], Wx[77];
  {
    const uint4* s4 = (const uint4*)(ws + WS_W + (size_t)(wg * 512 + lt) * STRD);
#pragma unroll
    for (int i = 0; i < 26; ++i) {
      uint4 v = s4[i];
      W2[4*i] = v.x; W2[4*i+1] = v.y; W2[4*i+2] = v.z; W2[4*i+3] = v.w;
    }
#pragma unroll
    for (int i = 0; i < 19; ++i) {
      uint4 v = s4[26 + i];
      Wx[4*i] = v.x; Wx[4*i+1] = v.y; Wx[4*i+2] = v.z; Wx[4*i+3] = v.w;
    }
    Wx[76] = ((const uint32_t*)s4)[180];
  }

  if (wg == 4) {
    // ---------------- output worker ----------------
    if (lt < 2) bsly[lt] = bl[lt];
    if (lt == 0) aborted = 0;
    __syncthreads();
    unsigned c3c[4] = {0, 0, 0, 0};
#pragma unroll 1
    for (int t = 0; t < T_TOT; ++t) {
      if (lt == 0) {
#pragma unroll
        for (int w = 0; w < 4; ++w) waitge(pg + (8 + w) * 32, &c3c[w], t + 1, &aborted);
      }
      __syncthreads();
      if (lt < 32) {
        int half = lt >> 4, d = lt & 15;
        Vecy[lt] = (d < 13) ? h3g[(t + 1) * 26 + half * 13 + d] : 0u;
      }
      __syncthreads();
      if (lt < 4) {
        int half = lt & 1;
        const uint4* V = (const uint4*)Vecy + half * 4;
        float g0 = 0.f, g1 = 0.f, g2 = 0.f, g3 = 0.f;
#pragma unroll
        for (int j = 0; j < 4; ++j) {
          uint4 hv = V[j];
          g0 = fdot2(W2[4*j],   hv.x, g0);
          g1 = fdot2(W2[4*j+1], hv.y, g1);
          g2 = fdot2(W2[4*j+2], hv.z, g2);
          g3 = fdot2(W2[4*j+3], hv.w, g3);
        }
        float s = (g0 + g1) + (g2 + g3);
        s += __shfl_xor(s, 1);
        if (!half) s += bsly[lt >> 1];
        float y1 = __shfl(s, 2);
        if (lt == 0) {
          out[2 * t] = s; out[2 * t + 1] = y1;
          yg[t] = packf16(s, y1);
        }
      }
      __syncthreads();
      if (lt == 0)
        __hip_atomic_store(pg + 12 * 32, (unsigned)(t + 1),
                           __ATOMIC_RELEASE, __HIP_MEMORY_SCOPE_AGENT);
    }
    return;
  }

  // ---------------- layer workers (wg 0..3) ----------------
  const int u1 = (wg < 3) ? 38 : 37, b1u = 38 * wg;
  const int u2 = (wg < 3) ? 63 : 62, b2u = 63 * wg;
  const int u3 = (wg < 3) ? 13 : 12, b3u = 13 * wg;

  if (lt < 4 * u1) { int g=(lt>=u1)+(lt>=2*u1)+(lt>=3*u1); int un=lt-g*u1; int R=g*151+b1u+un; bs1f[lt]=bih1[R]+bhh1[R]; }
  if (lt < 4 * u2) { int g=(lt>=u2)+(lt>=2*u2)+(lt>=3*u2); int un=lt-g*u2; int R=g*251+b2u+un; bs2f[lt]=bih2[R]+bhh2[R]; }
  if (lt < 4 * u3) { int g=(lt>=u3)+(lt>=2*u3)+(lt>=3*u3); int un=lt-g*u3; int R=g*51 +b3u+un; bs3f[lt]=bih3[R]+bhh3[R]; }
  if (lt == 0) aborted = 0;
  __syncthreads();

  float c1 = 0.f, c2 = 0.f, c3 = 0.f;
  unsigned c1c[4] = {0,0,0,0}, c2c[4] = {0,0,0,0}, c3c[4] = {0,0,0,0}, cy = 0;
  uint16_t* const h1u = (uint16_t*)h1g;
  uint16_t* const h2u = (uint16_t*)h2g;
  uint16_t* const h3u = (uint16_t*)h3g;

#pragma unroll 1
  for (int t = 0; t < T_TOT; ++t) {
    // ---------- P1: layer-1 ----------
    if (lt == 0 && t >= T_MAIN) waitge(pg + 12 * 32, &cy, (unsigned)t, &aborted);
    __syncthreads();
    if (lt < 77) Vec1[lt] = (lt < 76) ? h1g[t * 76 + lt]
                                      : ((t < T_MAIN) ? xg[t] : yg[t - 1]);
    __syncthreads();
    if (lt < 4 * u1) {
      const uint4* V = (const uint4*)Vec1;
      float g0 = bs1f[lt], g1 = 0.f, g2 = 0.f, g3 = 0.f;
#pragma unroll
      for (int j = 0; j < 19; ++j) {
        uint4 hv = V[j];
        g0 = fdot2(Wx[4*j],   hv.x, g0);
        g1 = fdot2(Wx[4*j+1], hv.y, g1);
        g2 = fdot2(Wx[4*j+2], hv.z, g2);
        g3 = fdot2(Wx[4*j+3], hv.w, g3);
      }
      g0 = fdot2(Wx[76], Vec1[76], g0);
      G[lt] = (g0 + g1) + (g2 + g3);
    }
    __syncthreads();
    if (lt < u1) {
      float gi = sigm(G[lt]), gf = sigm(G[u1 + lt]);
      float gg = tanhfast(G[2 * u1 + lt]), go = sigm(G[3 * u1 + lt]);
      c1 = gf * c1 + gi * gg;
      h1u[(t + 1) * 152 + b1u + lt] = f16b(go * tanhfast(c1));
    }
    __syncthreads();
    if (lt == 0)
      __hip_atomic_store(pg + wg * 32, (unsigned)(t + 1),
                         __ATOMIC_RELEASE, __HIP_MEMORY_SCOPE_AGENT);

    // ---------- P2: layer-2 ----------
    if (lt == 0) {
#pragma unroll
      for (int w = 0; w < 4; ++w) if (w != wg) waitge(pg + w * 32, &c1c[w], (unsigned)(t + 1), &aborted);
    }
    __syncthreads();
    if (lt < 208) {
      uint32_t v;
      if      (lt < 76)  v = h1g[(t + 1) * 76 + lt];
      else if (lt < 101) v = h2g[t * 126 + (lt - 76)];
      else if (lt < 104) v = 0u;
      else if (lt < 205) v = h2g[t * 126 + 25 + (lt - 104)];
      else               v = 0u;
      Vec2[lt] = v;
    }
    __syncthreads();
    if (lt < 8 * u2) {
      int r2 = lt >> 1, half = lt & 1;
      const uint4* V = (const uint4*)Vec2 + half * 26;
      float g0 = half ? 0.f : bs2f[r2], g1 = 0.f, g2 = 0.f, g3 = 0.f;
#pragma unroll
      for (int j = 0; j < 26; ++j) {
        uint4 hv = V[j];
        g0 = fdot2(W2[4*j],   hv.x, g0);
        g1 = fdot2(W2[4*j+1], hv.y, g1);
        g2 = fdot2(W2[4*j+2], hv.z, g2);
        g3 = fdot2(W2[4*j+3], hv.w, g3);
      }
      float s = (g0 + g1) + (g2 + g3);
      s += __shfl_xor(s, 1);
      if (!half) G[r2] = s;
    }
    __syncthreads();
    if (lt < u2) {
      float gi = sigm(G[lt]), gf = sigm(G[u2 + lt]);
      float gg = tanhfast(G[2 * u2 + lt]), go = sigm(G[3 * u2 + lt]);
      c2 = gf * c2 + gi * gg;
      h2u[(t + 1) * 252 + b2u + lt] = f16b(go * tanhfast(c2));
    }
    __syncthreads();
    if (lt == 0)
      __hip_atomic_store(pg + (4 + wg) * 32, (unsigned)(t + 1),
                         __ATOMIC_RELEASE, __HIP_MEMORY_SCOPE_AGENT);

    // ---------- P3: layer-3 ----------
    if (lt == 0) {
#pragma unroll
      for (int w = 0; w < 4; ++w) if (w != wg) {
        waitge(pg + (4 + w) * 32, &c2c[w], (unsigned)(t + 1), &aborted);
        waitge(pg + (8 + w) * 32, &c3c[w], (unsigned)t,       &aborted);
      }
    }
    __syncthreads();
    if (lt < 152) Vec3[lt] = (lt < 126) ? h2g[(t + 1) * 126 + lt]
                                        : h3g[t * 26 + (lt - 126)];
    __syncthreads();
    if (lt >= 152 && lt < 152 + 8 * u3) {
      int tt = lt - 152, r3 = tt >> 1, half = tt & 1;
      const uint4* V = (const uint4*)Vec3 + half * 19;
      float g0 = half ? 0.f : bs3f[r3], g1 = 0.f, g2 = 0.f, g3 = 0.f;
#pragma unroll
      for (int j = 0; j < 19; ++j) {
        uint4 hv = V[j];
        g0 = fdot2(Wx[4*j],   hv.x, g0);
        g1 = fdot2(Wx[4*j+1], hv.y, g1);
        g2 = fdot2(Wx[4*j+2], hv.z, g2);
        g3 = fdot2(Wx[4*j+3], hv.w, g3);
      }
      float s = (g0 + g1) + (g2 + g3);
      s += __shfl_xor(s, 1);
      if (!half) G[r3] = s;
    }
    __syncthreads();
    if (lt < u3) {
      float gi = sigm(G[lt]), gf = sigm(G[u3 + lt]);
      float gg = tanhfast(G[2 * u3 + lt]), go = sigm(G[3 * u3 + lt]);
      c3 = gf * c3 + gi * gg;
      h3u[(t + 1) * 52 + b3u + lt] = f16b(go * tanhfast(c3));
    }
    __syncthreads();
    if (lt == 0)
      __hip_atomic_store(pg + (8 + wg) * 32, (unsigned)(t + 1),
                         __ATOMIC_RELEASE, __HIP_MEMORY_SCOPE_AGENT);
  }
}

extern "C" void kernel_launch(void* const* d_in, const int* in_sizes, int n_in,
                              void* d_out, int out_size, void* d_ws, size_t ws_size,
                              hipStream_t stream) {
  (void)in_sizes; (void)n_in; (void)out_size; (void)ws_size;
  const float* x    = (const float*)d_in[0];
  const float* Wih1 = (const float*)d_in[1];
  const float* Whh1 = (const float*)d_in[2];
  const float* bih1 = (const float*)d_in[3];
  const float* bhh1 = (const float*)d_in[4];
  const float* Wih2 = (const float*)d_in[5];
  const float* Whh2 = (const float*)d_in[6];
  const float* bih2 = (const float*)d_in[7];
  const float* bhh2 = (const float*)d_in[8];
  const float* Wih3 = (const float*)d_in[9];
  const float* Whh3 = (const float*)d_in[10];
  const float* bih3 = (const float*)d_in[11];
  const float* bhh3 = (const float*)d_in[12];
  const float* Wl   = (const float*)d_in[13];
  const float* bl   = (const float*)d_in[14];

  uint32_t* ws = (uint32_t*)d_ws;   // needs ~6.6 MB

  prep<<<2625, 64, 0, stream>>>(x, Wih1, Whh1, Wih2, Whh2, Wih3, Whh3, Wl, ws);
  lstm5<<<5, NTHR, 0, stream>>>(ws, bih1, bhh1, bih2, bhh2, bih3, bhh3, bl,
                                (float*)d_out);
}

// Round 7
// 14412.283 us; speedup vs baseline: 8.2664x; 3.4637x over previous
//
#include <hip/hip_runtime.h>
#include <stdint.h>

#define T_MAIN 4096
#define T_TOT  5120

// ws dword offsets
#define O_W2   0            // 2*512*204 = 208896
#define O_W1   208896       // 512*80
#define O_W1B  249856       // 92*80
#define O_W3   257216       // 408*80 = 32640
#define O_WY   289856       // 2*32
#define O_X    289920       // 4096
#define O_H1T  294016       // 5121*152
#define O_H2AT 1072408      // 5121*126
#define O_H2BT 1717654      // 5121*125 -> end 2357779 dw (~9.4 MB)

typedef _Float16 f16;
typedef _Float16 f16x2 __attribute__((ext_vector_type(2)));

__device__ __forceinline__ float fdot2(uint32_t a, uint32_t b, float c) {
  return __builtin_amdgcn_fdot2(__builtin_bit_cast(f16x2, a),
                                __builtin_bit_cast(f16x2, b), c, false);
}
__device__ __forceinline__ uint32_t packf16(float a, float b) {
  f16x2 p = { (_Float16)a, (_Float16)b };
  return __builtin_bit_cast(uint32_t, p);
}
__device__ __forceinline__ uint16_t f16bits(float v) {
  return __builtin_bit_cast(uint16_t, (_Float16)v);
}
__device__ __forceinline__ float sigm(float x) { return 1.f / (1.f + __expf(-x)); }
__device__ __forceinline__ float tanhfast(float x) { return 2.f / (1.f + __expf(-2.f * x)) - 1.f; }

// ---------- prep: weight packing ----------
// L2 row layout (u16 slots [0,408)): [h1 k<151 |pad] [h2 units 0..125 |2pad] [h2 units 126..250 |3pad]
__device__ float l2w(int pw, int tid, int s, const float* Wih2, const float* Whh2) {
  int NGU = pw ? 125 : 126;
  if (tid >= 4 * NGU) return 0.f;
  int g = tid / NGU, u = tid - g * NGU, ug = pw ? 126 + u : u;
  int R = g * 251 + ug;
  if (s < 151) return Wih2[R * 151 + s];
  if (s < 152) return 0.f;
  if (s < 280) { int j = s - 152; return (j < 126) ? Whh2[R * 251 + j] : 0.f; }
  if (s < 408) { int j = s - 280; return (j < 125) ? Whh2[R * 251 + 126 + j] : 0.f; }
  return 0.f;
}
// L3 row layout (u16 slots [0,320)): [h2a 0..125|2pad][h2b 0..124|3pad][h3 0..50|13pad]
__device__ float l3w(int r3, int s, const float* Wih3, const float* Whh3) {
  if (s < 128) { return (s < 126) ? Wih3[r3 * 251 + s] : 0.f; }
  if (s < 256) { int j = s - 128; return (j < 125) ? Wih3[r3 * 251 + 126 + j] : 0.f; }
  if (s < 320) { int j = s - 256; return (j < 51) ? Whh3[r3 * 51 + j] : 0.f; }
  return 0.f;
}

__global__ void prep(const float* __restrict__ x,
                     const float* __restrict__ Wih1, const float* __restrict__ Whh1,
                     const float* __restrict__ Wih2, const float* __restrict__ Whh2,
                     const float* __restrict__ Wih3, const float* __restrict__ Whh3,
                     const float* __restrict__ Wl,
                     uint32_t* __restrict__ ws) {
  int b = blockIdx.x, lt = threadIdx.x;   // 64 threads
  if (b < 1024) {                          // L2 per-thread rows
    int pw = b >> 9, tid = b & 511;
    uint32_t* dst = ws + O_W2 + (size_t)(pw * 512 + tid) * 204;
    for (int d = lt; d < 204; d += 64)
      dst[d] = packf16(l2w(pw, tid, 2 * d, Wih2, Whh2),
                       l2w(pw, tid, 2 * d + 1, Wih2, Whh2));
  } else if (b < 1628) {                   // L1 rows (80-dw blocks: [xw][3 pad][19 uint4 h])
    int r = b - 1024;
    uint32_t* dst = ws + ((r < 512) ? (O_W1 + r * 80) : (O_W1B + (r - 512) * 80));
    for (int d = lt; d < 80; d += 64) {
      uint32_t v;
      if (d == 0)      v = packf16(Wih1[r * 2 + 0], Wih1[r * 2 + 1]);
      else if (d < 4)  v = 0u;
      else {
        int k0 = 2 * (d - 4), k1 = k0 + 1;
        v = packf16(k0 < 151 ? Whh1[r * 151 + k0] : 0.f,
                    k1 < 151 ? Whh1[r * 151 + k1] : 0.f);
      }
      dst[d] = v;
    }
  } else if (b < 2036) {                   // L3 half-rows (80 dw each = 160 u16 slots)
    int idx = b - 1628, r3 = idx >> 1, h = idx & 1;
    uint32_t* dst = ws + O_W3 + idx * 80;
    for (int d = lt; d < 80; d += 64) {
      int s0 = h * 160 + 2 * d;
      dst[d] = packf16(l3w(r3, s0, Wih3, Whh3), l3w(r3, s0 + 1, Wih3, Whh3));
    }
  } else if (b == 2036) {                  // Wl rows (2 x 32 dw over h3 slots [0,64))
    for (int d = lt; d < 64; d += 64) {
      int r = d >> 5, s0 = (d & 31) * 2;
      float v0 = (s0 < 51) ? Wl[r * 51 + s0] : 0.f;
      float v1 = (s0 + 1 < 51) ? Wl[r * 51 + s0 + 1] : 0.f;
      ws[O_WY + d] = packf16(v0, v1);
    }
  } else if (b == 2037) {                  // zero tag-slot 0 of each trace (tag 0 = initial state)
    for (int i = lt; i < 152; i += 64) ws[O_H1T + i] = 0u;
    for (int i = lt; i < 126; i += 64) ws[O_H2AT + i] = 0u;
    for (int i = lt; i < 125; i += 64) ws[O_H2BT + i] = 0u;
  } else {                                 // x -> f16 pairs
    int i = (b - 2038) * 64 + lt;
    if (i < T_MAIN) ws[O_X + i] = packf16(x[2 * i], x[2 * i + 1]);
  }
}

// ---------- tagged-slot primitives (relaxed agent atomics; tag+data in one dword) ----------
__device__ __forceinline__ uint32_t pollslot(uint32_t* p, uint32_t tag, volatile int* bail) {
  if (*bail) return 0u;
  tag &= 0xffffu;
  for (int i = 0; i < 4000000; ++i) {
    uint32_t v = __hip_atomic_load(p, __ATOMIC_RELAXED, __HIP_MEMORY_SCOPE_AGENT);
    if ((v & 0xffffu) == tag) return v;
    if ((i & 0xffff) == 0xffff && *bail) return 0u;
  }
  *bail = 1;                 // terminate instead of hanging (result garbage)
  return 0u;
}
__device__ __forceinline__ void pubslot(uint32_t* p, uint16_t bits, uint32_t tag) {
  __hip_atomic_store(p, ((uint32_t)bits << 16) | (tag & 0xffffu),
                     __ATOMIC_RELAXED, __HIP_MEMORY_SCOPE_AGENT);
}

__global__ __launch_bounds__(512, 2) __attribute__((amdgpu_waves_per_eu(2, 2)))
void lstm3(
    uint32_t* __restrict__ ws,
    const float* __restrict__ bih1, const float* __restrict__ bhh1,
    const float* __restrict__ bih2, const float* __restrict__ bhh2,
    const float* __restrict__ bih3, const float* __restrict__ bhh3,
    const float* __restrict__ bl, float* __restrict__ out) {
  const int wg = blockIdx.x, tid = threadIdx.x;
  __shared__ float G[604];
  __shared__ __align__(16) uint16_t Vbuf[408];   // pair: [h1 152][h2a 128][h2b 128]
  __shared__ __align__(16) uint16_t h1L[152];    // wg0: local h1 (f16)
  __shared__ __align__(16) uint16_t Vb3[320];    // wg0: [h2a 128][h2b 128][h3 64]
  __shared__ uint32_t yL;
  __shared__ int bailS;
  if (tid == 0) { bailS = 0; yL = 0u; }

  if (wg >= 1) {
    // ================= L2 pair (wg 1: units 0..125 ; wg 2: units 126..250) =================
    const int pw = wg - 1;
    const int NGU = pw ? 125 : 126;
    const int NG = 4 * NGU;
    const int OWN = pw ? 280 : 152;
    const int REM = pw ? 152 : 280;
    const int NREM = pw ? 126 : 125;
    uint32_t* const ownT = ws + (pw ? O_H2BT : O_H2AT);
    uint32_t* const remT = ws + (pw ? O_H2AT : O_H2BT);
    const int ownStr = pw ? 125 : 126;
    const int remStr = pw ? 126 : 125;

    uint32_t W2r[204];
    {
      const uint32_t* src = ws + O_W2 + (size_t)(pw * 512 + tid) * 204;
#pragma unroll
      for (int i = 0; i < 204; ++i) W2r[i] = src[i];
    }
    float bias = 0.f;
    if (tid < NG) {
      int g = tid / NGU, u = tid - g * NGU, ug = pw ? 126 + u : u;
      int R = g * 251 + ug;
      bias = bih2[R] + bhh2[R];
    }
    float c2 = 0.f;
    if (tid < 408) Vbuf[tid] = 0;
    __syncthreads();

#pragma unroll 1
    for (int t = 0; t < T_TOT; ++t) {
      // stage: h1(t) (slot t+1) + partner half h2(t-1) (slot t)
      if (tid < 151) {
        uint32_t v = pollslot(ws + O_H1T + (size_t)(t + 1) * 152 + tid, (uint32_t)(t + 1), &bailS);
        Vbuf[tid] = (uint16_t)(v >> 16);
      } else if (tid >= 160 && tid < 160 + NREM) {
        int j = tid - 160;
        uint32_t v = pollslot(remT + (size_t)t * remStr + j, (uint32_t)t, &bailS);
        Vbuf[REM + j] = (uint16_t)(v >> 16);
      }
      __syncthreads();
      // gates: 1 thread = 1 gate row, 51 uint4
      if (tid < NG) {
        const uint4* V = (const uint4*)Vbuf;
        float g0 = bias, g1 = 0.f, g2 = 0.f, g3 = 0.f;
#pragma unroll
        for (int j = 0; j < 51; ++j) {
          uint4 hv = V[j];
          g0 = fdot2(W2r[4 * j + 0], hv.x, g0);
          g1 = fdot2(W2r[4 * j + 1], hv.y, g1);
          g2 = fdot2(W2r[4 * j + 2], hv.z, g2);
          g3 = fdot2(W2r[4 * j + 3], hv.w, g3);
        }
        G[tid] = (g0 + g1) + (g2 + g3);
      }
      __syncthreads();
      // cell + publish own half (tagged, fire-and-forget)
      if (tid < NGU) {
        float gi = sigm(G[tid]), gf = sigm(G[NGU + tid]);
        float gg = tanhfast(G[2 * NGU + tid]), go = sigm(G[3 * NGU + tid]);
        c2 = gf * c2 + gi * gg;
        uint16_t bits = f16bits(go * tanhfast(c2));
        Vbuf[OWN + tid] = bits;
        pubslot(ownT + (size_t)(t + 1) * ownStr + tid, bits, (uint32_t)(t + 1));
      }
      __syncthreads();
    }
    return;
  }

  // ================= wg0: L1 + L3 + output =================
  uint32_t W1x, W1h[76], Wex[80];   // Wex by tid: [0,92) L1-extra row; 92/93 Wl row; [104,512) L3 half-row
  {
    const uint32_t* s1 = ws + O_W1 + (size_t)tid * 80;
    W1x = s1[0];
#pragma unroll
    for (int j = 0; j < 76; ++j) W1h[j] = s1[4 + j];
  }
#pragma unroll
  for (int j = 0; j < 80; ++j) Wex[j] = 0u;
  if (tid < 92) {
    const uint32_t* s2 = ws + O_W1B + (size_t)tid * 80;
    Wex[0] = s2[0];
#pragma unroll
    for (int j = 0; j < 76; ++j) Wex[1 + j] = s2[4 + j];
  } else if (tid == 92 || tid == 93) {
    const uint32_t* s2 = ws + O_WY + (size_t)(tid - 92) * 32;
#pragma unroll
    for (int j = 0; j < 32; ++j) Wex[j] = s2[j];
  } else if (tid >= 104) {
    const uint32_t* s2 = ws + O_W3 + (size_t)(tid - 104) * 80;
#pragma unroll
    for (int j = 0; j < 80; ++j) Wex[j] = s2[j];
  }
  float b1a = bih1[tid] + bhh1[tid];                       // row = tid (<512)
  float b1b = (tid < 92) ? (bih1[512 + tid] + bhh1[512 + tid]) : 0.f;
  float b3 = 0.f;
  if (tid >= 104 && ((tid - 104) & 1) == 0) {
    int r3 = (tid - 104) >> 1;
    b3 = bih3[r3] + bhh3[r3];
  }
  float by = (tid == 92 || tid == 93) ? bl[tid - 92] : 0.f;
  float c1 = 0.f, c3 = 0.f;
  if (tid < 152) h1L[tid] = 0;
  if (tid < 320) Vb3[tid] = 0;
  __syncthreads();

  // ---- Phase A: blast entire main-phase L1 (self-recurrent; x known) ----
#pragma unroll 1
  for (int t = 0; t < T_MAIN; ++t) {
    uint32_t xin = ws[O_X + t];
    const uint4* Hp = (const uint4*)h1L;
    {
      float g0 = fdot2(W1x, xin, b1a), g1 = 0.f, g2 = 0.f, g3 = 0.f;
#pragma unroll
      for (int j = 0; j < 19; ++j) {
        uint4 hv = Hp[j];
        g0 = fdot2(W1h[4 * j + 0], hv.x, g0);
        g1 = fdot2(W1h[4 * j + 1], hv.y, g1);
        g2 = fdot2(W1h[4 * j + 2], hv.z, g2);
        g3 = fdot2(W1h[4 * j + 3], hv.w, g3);
      }
      G[tid] = (g0 + g1) + (g2 + g3);
    }
    if (tid < 92) {
      float g0 = fdot2(Wex[0], xin, b1b), g1 = 0.f, g2 = 0.f, g3 = 0.f;
#pragma unroll
      for (int j = 0; j < 19; ++j) {
        uint4 hv = Hp[j];
        g0 = fdot2(Wex[1 + 4 * j], hv.x, g0);
        g1 = fdot2(Wex[2 + 4 * j], hv.y, g1);
        g2 = fdot2(Wex[3 + 4 * j], hv.z, g2);
        g3 = fdot2(Wex[4 + 4 * j], hv.w, g3);
      }
      G[512 + tid] = (g0 + g1) + (g2 + g3);
    }
    __syncthreads();
    if (tid < 151) {
      float gi = sigm(G[tid]), gf = sigm(G[151 + tid]);
      float gg = tanhfast(G[302 + tid]), go = sigm(G[453 + tid]);
      c1 = gf * c1 + gi * gg;
      uint16_t bits = f16bits(go * tanhfast(c1));
      h1L[tid] = bits;
      pubslot(ws + O_H1T + (size_t)(t + 1) * 152 + tid, bits, (uint32_t)(t + 1));
    }
    __syncthreads();
  }

  // ---- Phase B: main-phase L3 + y, streaming pair's h2 traces ----
#pragma unroll 1
  for (int t = 0; t < T_MAIN; ++t) {
    if (tid < 126) {
      uint32_t v = pollslot(ws + O_H2AT + (size_t)(t + 1) * 126 + tid, (uint32_t)(t + 1), &bailS);
      Vb3[tid] = (uint16_t)(v >> 16);
    } else if (tid >= 128 && tid < 253) {
      int j = tid - 128;
      uint32_t v = pollslot(ws + O_H2BT + (size_t)(t + 1) * 125 + j, (uint32_t)(t + 1), &bailS);
      Vb3[128 + j] = (uint16_t)(v >> 16);
    }
    __syncthreads();
    if (tid >= 104) {
      int it = tid - 104, r3 = it >> 1, hf = it & 1;
      const uint4* V = (const uint4*)Vb3 + hf * 20;
      float g0 = 0.f, g1 = 0.f, g2 = 0.f, g3 = 0.f;
#pragma unroll
      for (int j = 0; j < 20; ++j) {
        uint4 hv = V[j];
        g0 = fdot2(Wex[4 * j + 0], hv.x, g0);
        g1 = fdot2(Wex[4 * j + 1], hv.y, g1);
        g2 = fdot2(Wex[4 * j + 2], hv.z, g2);
        g3 = fdot2(Wex[4 * j + 3], hv.w, g3);
      }
      float s = (g0 + g1) + (g2 + g3);
      s += __shfl_xor(s, 1);
      if (!hf) G[r3] = s + b3;
    }
    __syncthreads();
    if (tid < 51) {
      float gi = sigm(G[tid]), gf = sigm(G[51 + tid]);
      float gg = tanhfast(G[102 + tid]), go = sigm(G[153 + tid]);
      c3 = gf * c3 + gi * gg;
      Vb3[256 + tid] = f16bits(go * tanhfast(c3));
    }
    __syncthreads();
    if (tid == 92 || tid == 93) {
      const uint4* V = (const uint4*)Vb3 + 32;   // h3 slots (u16 256..319)
      float g0 = by, g1 = 0.f, g2 = 0.f, g3 = 0.f;
#pragma unroll
      for (int j = 0; j < 8; ++j) {
        uint4 hv = V[j];
        g0 = fdot2(Wex[4 * j + 0], hv.x, g0);
        g1 = fdot2(Wex[4 * j + 1], hv.y, g1);
        g2 = fdot2(Wex[4 * j + 2], hv.z, g2);
        g3 = fdot2(Wex[4 * j + 3], hv.w, g3);
      }
      float y = (g0 + g1) + (g2 + g3);
      out[2 * t + (tid - 92)] = y;
      float y1 = __shfl(y, 29);          // tid 93 = lane 29 of wave 1
      if (tid == 92) yL = packf16(y, y1);
    }
    // no barrier needed: next stage writes Vb3[0,253) (disjoint from y's reads [256,320))
  }
  __syncthreads();

  // ---- Phase C: future steps (serial chain, y fed back) ----
#pragma unroll 1
  for (int t = T_MAIN; t < T_TOT; ++t) {
    uint32_t xin = yL;
    const uint4* Hp = (const uint4*)h1L;
    {
      float g0 = fdot2(W1x, xin, b1a), g1 = 0.f, g2 = 0.f, g3 = 0.f;
#pragma unroll
      for (int j = 0; j < 19; ++j) {
        uint4 hv = Hp[j];
        g0 = fdot2(W1h[4 * j + 0], hv.x, g0);
        g1 = fdot2(W1h[4 * j + 1], hv.y, g1);
        g2 = fdot2(W1h[4 * j + 2], hv.z, g2);
        g3 = fdot2(W1h[4 * j + 3], hv.w, g3);
      }
      G[tid] = (g0 + g1) + (g2 + g3);
    }
    if (tid < 92) {
      float g0 = fdot2(Wex[0], xin, b1b), g1 = 0.f, g2 = 0.f, g3 = 0.f;
#pragma unroll
      for (int j = 0; j < 19; ++j) {
        uint4 hv = Hp[j];
        g0 = fdot2(Wex[1 + 4 * j], hv.x, g0);
        g1 = fdot2(Wex[2 + 4 * j], hv.y, g1);
        g2 = fdot2(Wex[3 + 4 * j], hv.z, g2);
        g3 = fdot2(Wex[4 + 4 * j], hv.w, g3);
      }
      G[512 + tid] = (g0 + g1) + (g2 + g3);
    }
    __syncthreads();
    if (tid < 151) {
      float gi = sigm(G[tid]), gf = sigm(G[151 + tid]);
      float gg = tanhfast(G[302 + tid]), go = sigm(G[453 + tid]);
      c1 = gf * c1 + gi * gg;
      uint16_t bits = f16bits(go * tanhfast(c1));
      h1L[tid] = bits;
      pubslot(ws + O_H1T + (size_t)(t + 1) * 152 + tid, bits, (uint32_t)(t + 1));
    }
    __syncthreads();
    // L3 stage: wait for pair's h2(t)
    if (tid < 126) {
      uint32_t v = pollslot(ws + O_H2AT + (size_t)(t + 1) * 126 + tid, (uint32_t)(t + 1), &bailS);
      Vb3[tid] = (uint16_t)(v >> 16);
    } else if (tid >= 128 && tid < 253) {
      int j = tid - 128;
      uint32_t v = pollslot(ws + O_H2BT + (size_t)(t + 1) * 125 + j, (uint32_t)(t + 1), &bailS);
      Vb3[128 + j] = (uint16_t)(v >> 16);
    }
    __syncthreads();
    if (tid >= 104) {
      int it = tid - 104, r3 = it >> 1, hf = it & 1;
      const uint4* V = (const uint4*)Vb3 + hf * 20;
      float g0 = 0.f, g1 = 0.f, g2 = 0.f, g3 = 0.f;
#pragma unroll
      for (int j = 0; j < 20; ++j) {
        uint4 hv = V[j];
        g0 = fdot2(Wex[4 * j + 0], hv.x, g0);
        g1 = fdot2(Wex[4 * j + 1], hv.y, g1);
        g2 = fdot2(Wex[4 * j + 2], hv.z, g2);
        g3 = fdot2(Wex[4 * j + 3], hv.w, g3);
      }
      float s = (g0 + g1) + (g2 + g3);
      s += __shfl_xor(s, 1);
      if (!hf) G[r3] = s + b3;
    }
    __syncthreads();
    if (tid < 51) {
      float gi = sigm(G[tid]), gf = sigm(G[51 + tid]);
      float gg = tanhfast(G[102 + tid]), go = sigm(G[153 + tid]);
      c3 = gf * c3 + gi * gg;
      Vb3[256 + tid] = f16bits(go * tanhfast(c3));
    }
    __syncthreads();
    if (tid == 92 || tid == 93) {
      const uint4* V = (const uint4*)Vb3 + 32;   // h3 slots
      float g0 = by, g1 = 0.f, g2 = 0.f, g3 = 0.f;
#pragma unroll
      for (int j = 0; j < 8; ++j) {
        uint4 hv = V[j];
        g0 = fdot2(Wex[4 * j + 0], hv.x, g0);
        g1 = fdot2(Wex[4 * j + 1], hv.y, g1);
        g2 = fdot2(Wex[4 * j + 2], hv.z, g2);
        g3 = fdot2(Wex[4 * j + 3], hv.w, g3);
      }
      float y = (g0 + g1) + (g2 + g3);
      out[2 * t + (tid - 92)] = y;
      float y1 = __shfl(y, 29);
      if (tid == 92) yL = packf16(y, y1);
    }
    __syncthreads();   // yL must be visible to next iteration's L1
  }
}

extern "C" void kernel_launch(void* const* d_in, const int* in_sizes, int n_in,
                              void* d_out, int out_size, void* d_ws, size_t ws_size,
                              hipStream_t stream) {
  (void)in_sizes; (void)n_in; (void)out_size; (void)ws_size;
  const float* x    = (const float*)d_in[0];
  const float* Wih1 = (const float*)d_in[1];
  const float* Whh1 = (const float*)d_in[2];
  const float* bih1 = (const float*)d_in[3];
  const float* bhh1 = (const float*)d_in[4];
  const float* Wih2 = (const float*)d_in[5];
  const float* Whh2 = (const float*)d_in[6];
  const float* bih2 = (const float*)d_in[7];
  const float* bhh2 = (const float*)d_in[8];
  const float* Wih3 = (const float*)d_in[9];
  const float* Whh3 = (const float*)d_in[10];
  const float* bih3 = (const float*)d_in[11];
  const float* bhh3 = (const float*)d_in[12];
  const float* Wl   = (const float*)d_in[13];
  const float* bl   = (const float*)d_in[14];

  uint32_t* ws = (uint32_t*)d_ws;   // ~9.4 MB

  prep<<<2102, 64, 0, stream>>>(x, Wih1, Whh1, Wih2, Whh2, Wih3, Whh3, Wl, ws);
  lstm3<<<3, 512, 0, stream>>>(ws, bih1, bhh1, bih2, bhh2, bih3, bhh3, bl,
                               (float*)d_out);
}